// Round 10
// baseline (263.639 us; speedup 1.0000x reference)
//
#include <hip/hip_runtime.h>

#define TPB 1024

typedef _Float16 hf2 __attribute__((ext_vector_type(2)));

__device__ __forceinline__ hf2 as_h2(unsigned u) { return __builtin_bit_cast(hf2, u); }
__device__ __forceinline__ unsigned pk2h(float a, float b) {
    unsigned la = (unsigned)__builtin_bit_cast(unsigned short, (_Float16)a);
    unsigned hb = (unsigned)__builtin_bit_cast(unsigned short, (_Float16)b);
    return la | (hb << 16);
}
#define FDOT2(w, x, acc) __builtin_amdgcn_fdot2(as_h2(w), as_h2(x), (acc), false)

// Cross-lane adds OFF the DS pipe (VALU DPP): xor1 = quad_perm 0xB1,
// xor2 = quad_perm 0x4E, xor8 = row_ror:8 (0x128). xor4 has no DPP -> ds_swizzle.
#define DPPADD(v, CTRL) ((v) + __int_as_float(__builtin_amdgcn_update_dpp( \
    0, __float_as_int(v), (CTRL), 0xF, 0xF, false)))
#define SWZADD(v, OFF) ((v) + __int_as_float(__builtin_amdgcn_ds_swizzle( \
    __float_as_int(v), (OFF))))
#define RED4(v)  { v = DPPADD(v, 0xB1); v = DPPADD(v, 0x4E); }
#define RED16(v) { v = DPPADD(v, 0xB1); v = DPPADD(v, 0x4E); \
                   v = SWZADD(v, 0x101F); v = DPPADD(v, 0x128); }

#define RED64(v) { v += __shfl_xor(v,32,64); v += __shfl_xor(v,16,64); \
  v += __shfl_xor(v,8,64); v += __shfl_xor(v,4,64); v += __shfl_xor(v,2,64); \
  v += __shfl_xor(v,1,64); }

#define G4(M) M(0) M(1) M(2) M(3)

// r9 structure (validated correct, DS ~165 wave-instr/CU/eval) + the ONE fix:
// amdgpu_waves_per_eu(4,4). r9's __launch_bounds__(1024,1) let the allocator
// target 8 waves/EU (2 blocks/CU) -> 64-VGPR cap -> the ~110-reg demand
// spilled 30.6 MB. min=max=4 waves/EU pins the budget at 512/4 = 128 VGPR;
// one 16-wave block occupies exactly 4 waves/EU so no occupancy is lost
// (grid = 128 blocks < 256 CUs; a 2nd block/CU was unreachable anyway).
//  - thread covers 32 rows x 2 cols in BOTH matvecs (4 b128 broadcasts/phase)
//  - W1 AND W2 in registers (32+32 packed-f16-pair u32)
//  - cross-thread reduction via VALU DPP + 1 ds_swizzle (off the DS pipe)
//  - k-history/state replicated across the 16 lanes sharing an output pair
//  - 2 barriers/eval; trace/KL in thread-local accumulators, reduced once
__global__ __attribute__((amdgpu_flat_work_group_size(TPB, TPB),
                          amdgpu_waves_per_eu(4, 4)))
void vi_node_kernel(
    const float* __restrict__ x0, const float* __restrict__ W1,
    const float* __restrict__ b1, const float* __restrict__ u1,
    const float* __restrict__ W2, const float* __restrict__ b2,
    const int* __restrict__ nsp, float* __restrict__ out, int nB)
{
    const int s  = blockIdx.x;
    const int t  = threadIdx.x;
    const int l  = t & 63;
    const int w  = t >> 6;            // wave 0..15
    const int rg    = l & 3;          // H row-group: rows 32*rg .. 32*rg+31 (of 128)
    const int cpair = 16 * w + (l >> 2);  // H col-pair 0..255 -> cols 2cp, 2cp+1
    const int c0 = 2 * cpair, c1 = c0 + 1;
    const int rg4   = l & 15;         // P row-group: rows 32*rg4 .. +31 (of 512)
    const int jpair = 4 * w + (l >> 4);   // P col-pair 0..63 -> cols 2jp, 2jp+1
    const int j0 = 2 * jpair, j1 = j0 + 1;

    __shared__ __align__(16) unsigned xsPK[64];   // x, f16 pairs (pair k = elems 2k,2k+1)
    __shared__ __align__(16) unsigned aPKp[320];  // tanh acts, padded: pair k -> (k>>4)*20+(k&15)
    __shared__ float redA[16], redB[16], sqred[2];

    // ---- persistent W registers: f16 pairs, named scalars ----
#define DECLW(cc) unsigned wA##cc##_0, wA##cc##_1, wA##cc##_2, wA##cc##_3, \
                           wB##cc##_0, wB##cc##_1, wB##cc##_2, wB##cc##_3; \
                  unsigned zA##cc##_0, zA##cc##_1, zA##cc##_2, zA##cc##_3, \
                           zB##cc##_0, zB##cc##_1, zB##cc##_2, zB##cc##_3;
    G4(DECLW)

    // W1 pairs: reg (cc,m) = rows 32rg+2(4cc+m), +1 of col c0 (wA) / c1 (wB)
#define LDW1(cc) { const int r_ = 32 * rg + 8 * (cc); \
    wA##cc##_0 = pk2h(W1[(r_+0)*512+c0], W1[(r_+1)*512+c0]); \
    wA##cc##_1 = pk2h(W1[(r_+2)*512+c0], W1[(r_+3)*512+c0]); \
    wA##cc##_2 = pk2h(W1[(r_+4)*512+c0], W1[(r_+5)*512+c0]); \
    wA##cc##_3 = pk2h(W1[(r_+6)*512+c0], W1[(r_+7)*512+c0]); \
    wB##cc##_0 = pk2h(W1[(r_+0)*512+c1], W1[(r_+1)*512+c1]); \
    wB##cc##_1 = pk2h(W1[(r_+2)*512+c1], W1[(r_+3)*512+c1]); \
    wB##cc##_2 = pk2h(W1[(r_+4)*512+c1], W1[(r_+5)*512+c1]); \
    wB##cc##_3 = pk2h(W1[(r_+6)*512+c1], W1[(r_+7)*512+c1]); }
    G4(LDW1)

    // W2 pairs: reg (cc,m) = rows 32rg4+2(4cc+m), +1 of col j0 (zA) / j1 (zB)
#define LDW2(cc) { const int r_ = 32 * rg4 + 8 * (cc); \
    zA##cc##_0 = pk2h(W2[(r_+0)*128+j0], W2[(r_+1)*128+j0]); \
    zA##cc##_1 = pk2h(W2[(r_+2)*128+j0], W2[(r_+3)*128+j0]); \
    zA##cc##_2 = pk2h(W2[(r_+4)*128+j0], W2[(r_+5)*128+j0]); \
    zA##cc##_3 = pk2h(W2[(r_+6)*128+j0], W2[(r_+7)*128+j0]); \
    zB##cc##_0 = pk2h(W2[(r_+0)*128+j1], W2[(r_+1)*128+j1]); \
    zB##cc##_1 = pk2h(W2[(r_+2)*128+j1], W2[(r_+3)*128+j1]); \
    zB##cc##_2 = pk2h(W2[(r_+4)*128+j1], W2[(r_+5)*128+j1]); \
    zB##cc##_3 = pk2h(W2[(r_+6)*128+j1], W2[(r_+7)*128+j1]); }
    G4(LDW2)

    // ---- wdiag for H cols (exact fp32): partial over this thread's 32 i's ----
    float wd0 = 0.f, wd1 = 0.f;
#pragma unroll
    for (int i = 0; i < 32; ++i) {
        const int r_ = 32 * rg + i;
        wd0 = fmaf(W1[r_ * 512 + c0], W2[c0 * 128 + r_], wd0);
        wd1 = fmaf(W1[r_ * 512 + c1], W2[c1 * 128 + r_], wd1);
    }
    RED4(wd0) RED4(wd1)

    const float b1k0 = b1[c0], b1k1 = b1[c1];
    const float u1k0 = u1[c0], u1k1 = u1[c1];
    const float b2j0 = b2[j0], b2j1 = b2[j1];

    const int ns = nsp[0];
    const float dt = 1.f / (float)ns;

    // ---- init: xsPK, sumsq, register state ----
    if (t < 64) xsPK[t] = pk2h(x0[s * 128 + 2 * t], x0[s * 128 + 2 * t + 1]);
    if (t < 128) {
        float xv = x0[s * 128 + t];
        float sq = xv * xv;
        RED64(sq)
        if (l == 0) sqred[w] = sq;
    }
    float xc0 = x0[s * 128 + j0], xc1 = x0[s * 128 + j1];   // replicated x16
    float yc0 = xc0, yc1 = xc1;
    float k0_0=0.f,k0_1=0.f,k1_0=0.f,k1_1=0.f,k2_0=0.f,k2_1=0.f,
          k3_0=0.f,k3_1=0.f,k4_0=0.f,k4_1=0.f;
    float tr_loc = 0.f, dot_loc = 0.f;
    __syncthreads();

    // ---- per-eval compute groups ----
#define HM(cc) { const uint4 xq = *(const uint4*)&xsPK[16 * rg + 4 * (cc)]; \
    a0 = FDOT2(wA##cc##_0, xq.x, a0); a1 = FDOT2(wA##cc##_1, xq.y, a1); \
    a0 = FDOT2(wA##cc##_2, xq.z, a0); a1 = FDOT2(wA##cc##_3, xq.w, a1); \
    b0 = FDOT2(wB##cc##_0, xq.x, b0); b1v = FDOT2(wB##cc##_1, xq.y, b1v); \
    b0 = FDOT2(wB##cc##_2, xq.z, b0); b1v = FDOT2(wB##cc##_3, xq.w, b1v); }

#define PM(cc) { const uint4 aq = *(const uint4*)&aPKp[20 * rg4 + 4 * (cc)]; \
    p0 = FDOT2(zA##cc##_0, aq.x, p0); p1 = FDOT2(zA##cc##_1, aq.y, p1); \
    p0 = FDOT2(zA##cc##_2, aq.z, p0); p1 = FDOT2(zA##cc##_3, aq.w, p1); \
    q0 = FDOT2(zB##cc##_0, aq.x, q0); q1 = FDOT2(zB##cc##_1, aq.y, q1); \
    q0 = FDOT2(zB##cc##_2, aq.z, q0); q1 = FDOT2(zB##cc##_3, aq.w, q1); }

// One RHS eval + state advance. 2 barriers. CW = dopri B-weight of this stage.
#define EVAL(CW, TVAL, KST0, KST1, XN0, XN1, LAST)                             \
    {                                                                          \
        float a0=0.f, a1=0.f, b0=0.f, b1v=0.f;                                 \
        HM(0) HM(1) HM(2) HM(3)                                                \
        float sA = a0 + a1, sB = b0 + b1v;                                     \
        RED4(sA) RED4(sB)                        /* sum over rg (4 lanes) */   \
        float h0 = fmaf((TVAL), u1k0, b1k0) + sA;                              \
        float h1 = fmaf((TVAL), u1k1, b1k1) + sB;                              \
        float aa0 = 1.f - 2.f / (__expf(2.f * h0) + 1.f);                      \
        float aa1 = 1.f - 2.f / (__expf(2.f * h1) + 1.f);                      \
        if (rg == 0)                                                           \
            aPKp[(cpair >> 4) * 20 + (cpair & 15)] = pk2h(aa0, aa1);           \
        tr_loc = fmaf((CW), fmaf(-aa0, aa0, 1.f) * wd0                         \
                          + fmaf(-aa1, aa1, 1.f) * wd1, tr_loc);               \
        __syncthreads();                          /* B1: aPKp ready */         \
        float p0=0.f, p1=0.f, q0=0.f, q1=0.f;                                  \
        PM(0) PM(1) PM(2) PM(3)                                                \
        float sp = p0 + p1, sq_ = q0 + q1;                                     \
        RED16(sp) RED16(sq_)                      /* sum over rg4 (16 lanes) */\
        float dx0 = sp + b2j0, dx1 = sq_ + b2j1;                               \
        dot_loc = fmaf((CW), xc0 * dx0 + xc1 * dx1, dot_loc);                  \
        KST0; KST1;                                                            \
        xc0 = (XN0); xc1 = (XN1);                                              \
        if (LAST) { yc0 = xc0; yc1 = xc1; }                                    \
        if ((l & 15) == 0) xsPK[jpair] = pk2h(xc0, xc1);                       \
        __syncthreads();                          /* B2: xsPK ready */         \
    }

    for (int n = 0; n < ns; ++n) {
        const float tn = (float)n;

        EVAL((float)(35.0/384.0), tn * dt, k0_0 = dx0, k0_1 = dx1,
             fmaf(dt, 0.2f * dx0, yc0), fmaf(dt, 0.2f * dx1, yc1), 0)

        EVAL(0.0f, (tn + 0.2f) * dt, k1_0 = dx0, k1_1 = dx1,
             yc0 + dt * (0.075f * k0_0 + 0.225f * dx0),
             yc1 + dt * (0.075f * k0_1 + 0.225f * dx1), 0)

        EVAL((float)(500.0/1113.0), (tn + 0.3f) * dt, k2_0 = dx0, k2_1 = dx1,
             yc0 + dt * ((float)(44.0/45.0) * k0_0 + (float)(-56.0/15.0) * k1_0
                       + (float)(32.0/9.0)  * dx0),
             yc1 + dt * ((float)(44.0/45.0) * k0_1 + (float)(-56.0/15.0) * k1_1
                       + (float)(32.0/9.0)  * dx1), 0)

        EVAL((float)(125.0/192.0), (tn + 0.8f) * dt, k3_0 = dx0, k3_1 = dx1,
             yc0 + dt * ((float)(19372.0/6561.0) * k0_0 + (float)(-25360.0/2187.0) * k1_0
                       + (float)(64448.0/6561.0) * k2_0 + (float)(-212.0/729.0)    * dx0),
             yc1 + dt * ((float)(19372.0/6561.0) * k0_1 + (float)(-25360.0/2187.0) * k1_1
                       + (float)(64448.0/6561.0) * k2_1 + (float)(-212.0/729.0)    * dx1), 0)

        EVAL((float)(-2187.0/6784.0), (tn + (float)(8.0/9.0)) * dt, k4_0 = dx0, k4_1 = dx1,
             yc0 + dt * ((float)(9017.0/3168.0)  * k0_0 + (float)(-355.0/33.0) * k1_0
                       + (float)(46732.0/5247.0) * k2_0 + (float)(49.0/176.0)  * k3_0
                       + (float)(-5103.0/18656.0) * dx0),
             yc1 + dt * ((float)(9017.0/3168.0)  * k0_1 + (float)(-355.0/33.0) * k1_1
                       + (float)(46732.0/5247.0) * k2_1 + (float)(49.0/176.0)  * k3_1
                       + (float)(-5103.0/18656.0) * dx1), 0)

        EVAL((float)(11.0/84.0), (tn + 1.0f) * dt, (void)0, (void)0,
             yc0 + dt * ((float)(35.0/384.0)  * k0_0 + (float)(500.0/1113.0)   * k2_0
                       + (float)(125.0/192.0) * k3_0 + (float)(-2187.0/6784.0) * k4_0
                       + (float)(11.0/84.0)   * dx0),
             yc1 + dt * ((float)(35.0/384.0)  * k0_1 + (float)(500.0/1113.0)   * k2_1
                       + (float)(125.0/192.0) * k3_1 + (float)(-2187.0/6784.0) * k4_1
                       + (float)(11.0/84.0)   * dx1), 1)
    }

    // ---- final reductions (once): tr (x4 replicated), dot (x16 replicated) ----
    {
        float tv = tr_loc;  RED64(tv)  if (l == 0) redA[w] = tv;
        float dv = dot_loc; RED64(dv)  if (l == 0) redB[w] = dv;
    }
    __syncthreads();

    // ---- outputs: z (B,D) | log_px (B) | kl (B) ----
    if ((l & 15) == 0) {
        out[s * 128 + j0] = yc0;
        out[s * 128 + j1] = yc1;
    }
    if (t == 0) {
        float TRs = 0.f, DOs = 0.f;
#pragma unroll
        for (int ww = 0; ww < 16; ++ww) { TRs += redA[ww]; DOs += redB[ww]; }
        const float TR = TRs * dt * 0.25f;          // 4x lane replication
        const float DO = DOs * dt * (1.f / 16.f);   // 16x lane replication
        const float LOG2PI = 1.8378770664093454f;
        float lpx0 = -0.5f * (sqred[0] + sqred[1]) - 0.5f * 128.f * LOG2PI;
        out[nB * 128 + s]      = lpx0 - TR;
        out[nB * 128 + nB + s] = DO - TR;
    }
}

extern "C" void kernel_launch(void* const* d_in, const int* in_sizes, int n_in,
                              void* d_out, int out_size, void* d_ws, size_t ws_size,
                              hipStream_t stream) {
    const float* x0 = (const float*)d_in[0];
    const float* W1 = (const float*)d_in[1];
    const float* b1 = (const float*)d_in[2];
    const float* u1 = (const float*)d_in[3];
    const float* W2 = (const float*)d_in[4];
    const float* b2 = (const float*)d_in[5];
    const int*  nsp = (const int*)d_in[6];
    float* out = (float*)d_out;
    const int nB = in_sizes[0] / 128;   // 128 samples

    hipLaunchKernelGGL(vi_node_kernel, dim3(nB), dim3(TPB), 0, stream,
                       x0, W1, b1, u1, W2, b2, nsp, out, nB);
}

// Round 12
// 226.312 us; speedup vs baseline: 1.1649x; 1.1649x over previous
//
#include <hip/hip_runtime.h>

#define TPB 512

typedef _Float16 hf2 __attribute__((ext_vector_type(2)));

__device__ __forceinline__ hf2 as_h2(unsigned u) { return __builtin_bit_cast(hf2, u); }
__device__ __forceinline__ unsigned pk2h(float a, float b) {
    unsigned la = (unsigned)__builtin_bit_cast(unsigned short, (_Float16)a);
    unsigned hb = (unsigned)__builtin_bit_cast(unsigned short, (_Float16)b);
    return la | (hb << 16);
}
#define FDOT2(w, x, acc) __builtin_amdgcn_fdot2(as_h2(w), as_h2(x), (acc), false)
#define UPa(u) ((float)(as_h2(u).x))
#define UPb(u) ((float)(as_h2(u).y))

// All-DPP cross-lane sums (VALU pipe, zero DS):
// xor1 = quad_perm[1,0,3,2]=0xB1, xor2 = quad_perm[2,3,0,1]=0x4E,
// row_ror:4 = 0x124, row_ror:8 = 0x128 (rotate within 16-lane row).
#define DPPADD(v, CTRL) ((v) + __int_as_float(__builtin_amdgcn_update_dpp( \
    0, __float_as_int(v), (CTRL), 0xF, 0xF, false)))
#define RED4(v)  { v = DPPADD(v, 0xB1); v = DPPADD(v, 0x4E); }
#define RED16(v) { v = DPPADD(v, 0xB1); v = DPPADD(v, 0x4E); \
                   v = DPPADD(v, 0x124); v = DPPADD(v, 0x128); }
#define RED64(v) { v += __shfl_xor(v,32,64); v += __shfl_xor(v,16,64); \
  v += __shfl_xor(v,8,64); v += __shfl_xor(v,4,64); v += __shfl_xor(v,2,64); \
  v += __shfl_xor(v,1,64); }

#define G16(M) M(0) M(1) M(2) M(3) M(4) M(5) M(6) M(7) M(8) M(9) M(10) M(11) \
  M(12) M(13) M(14) M(15)

// Empirical law (r1-r10): VGPR cap = 65536/TPB, immovable by launch_bounds or
// amdgpu_waves_per_eu. TPB=512 -> 128 VGPR. Design fits ~118:
//  - W1 in regs: 64 u32 f16-pairs (thread = 32 rows x 4 cols, forced minimum)
//  - W2 in LDS (128 KB), XOR-swizzled by rg4 so the 16 lanes that share a
//    column land on different banks (2 lanes/bank = free, m136)
//  - C=4 tiling: x-read 4 b128, a-read 4 b128 per eval (vs r5's 32 broadcasts)
//  - reductions all-DPP (xor1/xor2/ror4/ror8) - zero DS, no ds_swizzle
//  - k-history f16-packed (10 u32), biases f16-packed, 2 barriers/eval
//  - W1/W2 staged coalescedly via LDS; trace/KL thread-local, reduced once
__global__ __launch_bounds__(TPB, 1) void vi_node_kernel(
    const float* __restrict__ x0, const float* __restrict__ W1,
    const float* __restrict__ b1, const float* __restrict__ u1,
    const float* __restrict__ W2, const float* __restrict__ b2,
    const int* __restrict__ nsp, float* __restrict__ out, int nB)
{
    const int s  = blockIdx.x;
    const int t  = threadIdx.x;
    const int l  = t & 63;
    const int w  = t >> 6;       // wave 0..7
    const int rg  = t & 3;       // H row-group: rows 32rg..32rg+31 (of 128)
    const int cg  = t >> 2;      // H col-group: cols 4cg..4cg+3 (of 512)
    const int rg4 = t & 15;      // P row-group: rows 32rg4..32rg4+31 (of 512)
    const int jg  = t >> 4;      // P col-group: cols 4jg..4jg+3 (of 128)

    __shared__ __align__(16) unsigned BIG[32768];   // 128 KB: W1 staging, then W2L
    __shared__ __align__(16) unsigned xsPK[64];     // x f16 pairs
    __shared__ __align__(16) unsigned aPKp[320];    // tanh acts, padded (16->20)
    __shared__ float redA[8], redB[8], sqred[2];

    // ---- 1) stage W1 as f16 pairs into BIG (coalesced) ----
    for (int idx = t; idx < 32768; idx += TPB) {
        const int rp = idx >> 9, col = idx & 511;
        BIG[(rp << 9) + col] =
            pk2h(W1[(2 * rp) * 512 + col], W1[(2 * rp + 1) * 512 + col]);
    }
    __syncthreads();

    // ---- 2) W1 regs: w1_i_m = rows (2(16rg+i), +1) of col 4cg+m ----
#define DECLW1(i) unsigned w1_##i##_0, w1_##i##_1, w1_##i##_2, w1_##i##_3;
    G16(DECLW1)
#define LDW1(i) { const uint4 v_ = *(const uint4*)&BIG[((16*rg + (i)) << 9) + 4*cg]; \
    w1_##i##_0 = v_.x; w1_##i##_1 = v_.y; w1_##i##_2 = v_.z; w1_##i##_3 = v_.w; }
    G16(LDW1)

    // wdiag partials over this thread's 32 rows; RED4 -> full column sums
    float wd0 = 0.f, wd1 = 0.f, wd2 = 0.f, wd3 = 0.f;
#define WDI(i) { const int r2_ = 2 * (16 * rg + (i)); \
    wd0 = FDOT2(w1_##i##_0, pk2h(W2[(4*cg+0)*128 + r2_], W2[(4*cg+0)*128 + r2_ + 1]), wd0); \
    wd1 = FDOT2(w1_##i##_1, pk2h(W2[(4*cg+1)*128 + r2_], W2[(4*cg+1)*128 + r2_ + 1]), wd1); \
    wd2 = FDOT2(w1_##i##_2, pk2h(W2[(4*cg+2)*128 + r2_], W2[(4*cg+2)*128 + r2_ + 1]), wd2); \
    wd3 = FDOT2(w1_##i##_3, pk2h(W2[(4*cg+3)*128 + r2_], W2[(4*cg+3)*128 + r2_ + 1]), wd3); }
    G16(WDI)
    RED4(wd0) RED4(wd1) RED4(wd2) RED4(wd3)

    __syncthreads();   // all W1-staging reads complete before overwrite

    // ---- 3) stage W2 into BIG, XOR-swizzled: store col c at c^((rp>>4)&7)<<2 ----
    for (int idx = t; idx < 32768; idx += TPB) {
        const int rp = idx >> 7, c = idx & 127;
        BIG[(rp << 7) + (c ^ (((rp >> 4) & 7) << 2))] =
            pk2h(W2[(2 * rp) * 128 + c], W2[(2 * rp + 1) * 128 + c]);
    }
    if (t < 64) xsPK[t] = pk2h(x0[s * 128 + 2 * t], x0[s * 128 + 2 * t + 1]);
    if (t < 128) {
        float xv = x0[s * 128 + t];
        float sq = xv * xv;
        RED64(sq)
        if (l == 0) sqred[w] = sq;
    }

    // packed biases (f16 pairs)
    const unsigned b1p_a = pk2h(b1[4*cg+0], b1[4*cg+1]);
    const unsigned b1p_b = pk2h(b1[4*cg+2], b1[4*cg+3]);
    const unsigned u1p_a = pk2h(u1[4*cg+0], u1[4*cg+1]);
    const unsigned u1p_b = pk2h(u1[4*cg+2], u1[4*cg+3]);
    const unsigned b2p_a = pk2h(b2[4*jg+0], b2[4*jg+1]);
    const unsigned b2p_b = pk2h(b2[4*jg+2], b2[4*jg+3]);

    // state (replicated across the 16 lanes sharing jg)
    float xc0 = x0[s*128 + 4*jg+0], xc1 = x0[s*128 + 4*jg+1];
    float xc2 = x0[s*128 + 4*jg+2], xc3 = x0[s*128 + 4*jg+3];
    float yc0 = xc0, yc1 = xc1, yc2 = xc2, yc3 = xc3;
    unsigned k0a=0,k0b=0,k1a=0,k1b=0,k2a=0,k2b=0,k3a=0,k3b=0,k4a=0,k4b=0;
    float tr_loc = 0.f, dot_loc = 0.f;

    const int ns = nsp[0];
    const float dt = 1.f / (float)ns;

    // precomputed LDS offsets
    const int xoff  = 16 * rg;                           // + 4cc
    const int aoff  = 20 * rg4;                          // + 4cc (padded layout)
    const int w2off = (rg4 << 11) + ((jg ^ (rg4 & 7)) << 2);  // + i<<7
    const int apk_w = (cg >> 3) * 20 + ((2 * cg) & 15);  // aPKp write (2 u32)
    const int xs_w  = 2 * jg;                            // xsPK write (2 u32)

    __syncthreads();

    // ---- per-eval compute groups ----
#define HM(cc, i0, i1, i2, i3) { const uint4 xq = *(const uint4*)&xsPK[xoff + 4*(cc)]; \
    a0  = FDOT2(w1_##i0##_0, xq.x, a0);  a1f = FDOT2(w1_##i0##_1, xq.x, a1f); \
    a2  = FDOT2(w1_##i0##_2, xq.x, a2);  a3  = FDOT2(w1_##i0##_3, xq.x, a3); \
    a0  = FDOT2(w1_##i1##_0, xq.y, a0);  a1f = FDOT2(w1_##i1##_1, xq.y, a1f); \
    a2  = FDOT2(w1_##i1##_2, xq.y, a2);  a3  = FDOT2(w1_##i1##_3, xq.y, a3); \
    a0  = FDOT2(w1_##i2##_0, xq.z, a0);  a1f = FDOT2(w1_##i2##_1, xq.z, a1f); \
    a2  = FDOT2(w1_##i2##_2, xq.z, a2);  a3  = FDOT2(w1_##i2##_3, xq.z, a3); \
    a0  = FDOT2(w1_##i3##_0, xq.w, a0);  a1f = FDOT2(w1_##i3##_1, xq.w, a1f); \
    a2  = FDOT2(w1_##i3##_2, xq.w, a2);  a3  = FDOT2(w1_##i3##_3, xq.w, a3); }

#define PMJ(cc, j, AE) { const uint4 wq = *(const uint4*)&BIG[w2off + ((4*(cc)+(j)) << 7)]; \
    p0 = FDOT2(wq.x, AE, p0); p1 = FDOT2(wq.y, AE, p1); \
    p2 = FDOT2(wq.z, AE, p2); p3 = FDOT2(wq.w, AE, p3); }
#define PM(cc) { const uint4 aq = *(const uint4*)&aPKp[aoff + 4*(cc)]; \
    PMJ(cc,0,aq.x) PMJ(cc,1,aq.y) PMJ(cc,2,aq.z) PMJ(cc,3,aq.w) }

// One RHS eval + state advance. 2 barriers.
#define EVAL(CW, TVAL, KST, XN0, XN1, XN2, XN3, LAST)                          \
    {                                                                          \
        float a0 = 0.f, a1f = 0.f, a2 = 0.f, a3 = 0.f;                         \
        HM(0, 0,1,2,3) HM(1, 4,5,6,7) HM(2, 8,9,10,11) HM(3, 12,13,14,15)      \
        RED4(a0) RED4(a1f) RED4(a2) RED4(a3)                                   \
        if (rg == 0) {                                                         \
            const float tv_ = (TVAL);                                          \
            float h0 = fmaf(tv_, UPa(u1p_a), UPa(b1p_a)) + a0;                 \
            float h1 = fmaf(tv_, UPb(u1p_a), UPb(b1p_a)) + a1f;                \
            float h2 = fmaf(tv_, UPa(u1p_b), UPa(b1p_b)) + a2;                 \
            float h3 = fmaf(tv_, UPb(u1p_b), UPb(b1p_b)) + a3;                 \
            float t0 = 1.f - 2.f / (__expf(2.f * h0) + 1.f);                   \
            float t1 = 1.f - 2.f / (__expf(2.f * h1) + 1.f);                   \
            float t2 = 1.f - 2.f / (__expf(2.f * h2) + 1.f);                   \
            float t3 = 1.f - 2.f / (__expf(2.f * h3) + 1.f);                   \
            *(uint2*)&aPKp[apk_w] = make_uint2(pk2h(t0, t1), pk2h(t2, t3));    \
            tr_loc = fmaf((CW), fmaf(-t0, t0, 1.f) * wd0                       \
                               + fmaf(-t1, t1, 1.f) * wd1                      \
                               + fmaf(-t2, t2, 1.f) * wd2                      \
                               + fmaf(-t3, t3, 1.f) * wd3, tr_loc);            \
        }                                                                      \
        __syncthreads();                          /* B1: aPKp ready */         \
        float p0 = 0.f, p1 = 0.f, p2 = 0.f, p3 = 0.f;                          \
        PM(0) PM(1) PM(2) PM(3)                                                \
        RED16(p0) RED16(p1) RED16(p2) RED16(p3)                                \
        float dx0 = p0 + UPa(b2p_a), dx1 = p1 + UPb(b2p_a);                    \
        float dx2 = p2 + UPa(b2p_b), dx3 = p3 + UPb(b2p_b);                    \
        dot_loc = fmaf((CW), xc0*dx0 + xc1*dx1 + xc2*dx2 + xc3*dx3, dot_loc);  \
        KST;                                                                   \
        float K00 = UPa(k0a), K01 = UPb(k0a), K02 = UPa(k0b), K03 = UPb(k0b);  \
        float K10 = UPa(k1a), K11 = UPb(k1a), K12 = UPa(k1b), K13 = UPb(k1b);  \
        float K20 = UPa(k2a), K21 = UPb(k2a), K22 = UPa(k2b), K23 = UPb(k2b);  \
        float K30 = UPa(k3a), K31 = UPb(k3a), K32 = UPa(k3b), K33 = UPb(k3b);  \
        float K40 = UPa(k4a), K41 = UPb(k4a), K42 = UPa(k4b), K43 = UPb(k4b);  \
        (void)K00;(void)K01;(void)K02;(void)K03;(void)K10;(void)K11;(void)K12; \
        (void)K13;(void)K20;(void)K21;(void)K22;(void)K23;(void)K30;(void)K31; \
        (void)K32;(void)K33;(void)K40;(void)K41;(void)K42;(void)K43;           \
        float xn0 = (XN0), xn1 = (XN1), xn2 = (XN2), xn3 = (XN3);              \
        xc0 = xn0; xc1 = xn1; xc2 = xn2; xc3 = xn3;                            \
        if (LAST) { yc0 = xn0; yc1 = xn1; yc2 = xn2; yc3 = xn3; }              \
        if ((l & 15) == 0)                                                     \
            *(uint2*)&xsPK[xs_w] = make_uint2(pk2h(xn0, xn1), pk2h(xn2, xn3)); \
        __syncthreads();                          /* B2: xsPK ready */         \
    }

    for (int n = 0; n < ns; ++n) {
        const float tn = (float)n;

        EVAL((float)(35.0/384.0), tn * dt,
             (k0a = pk2h(dx0,dx1), k0b = pk2h(dx2,dx3)),
             fmaf(dt, 0.2f*dx0, yc0), fmaf(dt, 0.2f*dx1, yc1),
             fmaf(dt, 0.2f*dx2, yc2), fmaf(dt, 0.2f*dx3, yc3), 0)

        EVAL(0.0f, (tn + 0.2f) * dt,
             (k1a = pk2h(dx0,dx1), k1b = pk2h(dx2,dx3)),
             yc0 + dt*(0.075f*K00 + 0.225f*dx0), yc1 + dt*(0.075f*K01 + 0.225f*dx1),
             yc2 + dt*(0.075f*K02 + 0.225f*dx2), yc3 + dt*(0.075f*K03 + 0.225f*dx3), 0)

        EVAL((float)(500.0/1113.0), (tn + 0.3f) * dt,
             (k2a = pk2h(dx0,dx1), k2b = pk2h(dx2,dx3)),
             yc0 + dt*((float)(44.0/45.0)*K00 + (float)(-56.0/15.0)*K10 + (float)(32.0/9.0)*dx0),
             yc1 + dt*((float)(44.0/45.0)*K01 + (float)(-56.0/15.0)*K11 + (float)(32.0/9.0)*dx1),
             yc2 + dt*((float)(44.0/45.0)*K02 + (float)(-56.0/15.0)*K12 + (float)(32.0/9.0)*dx2),
             yc3 + dt*((float)(44.0/45.0)*K03 + (float)(-56.0/15.0)*K13 + (float)(32.0/9.0)*dx3), 0)

        EVAL((float)(125.0/192.0), (tn + 0.8f) * dt,
             (k3a = pk2h(dx0,dx1), k3b = pk2h(dx2,dx3)),
             yc0 + dt*((float)(19372.0/6561.0)*K00 + (float)(-25360.0/2187.0)*K10
                     + (float)(64448.0/6561.0)*K20 + (float)(-212.0/729.0)*dx0),
             yc1 + dt*((float)(19372.0/6561.0)*K01 + (float)(-25360.0/2187.0)*K11
                     + (float)(64448.0/6561.0)*K21 + (float)(-212.0/729.0)*dx1),
             yc2 + dt*((float)(19372.0/6561.0)*K02 + (float)(-25360.0/2187.0)*K12
                     + (float)(64448.0/6561.0)*K22 + (float)(-212.0/729.0)*dx2),
             yc3 + dt*((float)(19372.0/6561.0)*K03 + (float)(-25360.0/2187.0)*K13
                     + (float)(64448.0/6561.0)*K23 + (float)(-212.0/729.0)*dx3), 0)

        EVAL((float)(-2187.0/6784.0), (tn + (float)(8.0/9.0)) * dt,
             (k4a = pk2h(dx0,dx1), k4b = pk2h(dx2,dx3)),
             yc0 + dt*((float)(9017.0/3168.0)*K00 + (float)(-355.0/33.0)*K10
                     + (float)(46732.0/5247.0)*K20 + (float)(49.0/176.0)*K30
                     + (float)(-5103.0/18656.0)*dx0),
             yc1 + dt*((float)(9017.0/3168.0)*K01 + (float)(-355.0/33.0)*K11
                     + (float)(46732.0/5247.0)*K21 + (float)(49.0/176.0)*K31
                     + (float)(-5103.0/18656.0)*dx1),
             yc2 + dt*((float)(9017.0/3168.0)*K02 + (float)(-355.0/33.0)*K12
                     + (float)(46732.0/5247.0)*K22 + (float)(49.0/176.0)*K32
                     + (float)(-5103.0/18656.0)*dx2),
             yc3 + dt*((float)(9017.0/3168.0)*K03 + (float)(-355.0/33.0)*K13
                     + (float)(46732.0/5247.0)*K23 + (float)(49.0/176.0)*K33
                     + (float)(-5103.0/18656.0)*dx3), 0)

        EVAL((float)(11.0/84.0), (tn + 1.0f) * dt, (void)0,
             yc0 + dt*((float)(35.0/384.0)*K00 + (float)(500.0/1113.0)*K20
                     + (float)(125.0/192.0)*K30 + (float)(-2187.0/6784.0)*K40
                     + (float)(11.0/84.0)*dx0),
             yc1 + dt*((float)(35.0/384.0)*K01 + (float)(500.0/1113.0)*K21
                     + (float)(125.0/192.0)*K31 + (float)(-2187.0/6784.0)*K41
                     + (float)(11.0/84.0)*dx1),
             yc2 + dt*((float)(35.0/384.0)*K02 + (float)(500.0/1113.0)*K22
                     + (float)(125.0/192.0)*K32 + (float)(-2187.0/6784.0)*K42
                     + (float)(11.0/84.0)*dx2),
             yc3 + dt*((float)(35.0/384.0)*K03 + (float)(500.0/1113.0)*K23
                     + (float)(125.0/192.0)*K33 + (float)(-2187.0/6784.0)*K43
                     + (float)(11.0/84.0)*dx3), 1)
    }

    // ---- final reductions: tr (rg==0 lanes only, each col once), dot (x16) ----
    {
        float tv = tr_loc;  RED64(tv)  if (l == 0) redA[w] = tv;
        float dv = dot_loc; RED64(dv)  if (l == 0) redB[w] = dv;
    }
    __syncthreads();

    // ---- outputs: z (B,D) | log_px (B) | kl (B) ----
    if ((l & 15) == 0) {
        out[s * 128 + 4*jg + 0] = yc0;
        out[s * 128 + 4*jg + 1] = yc1;
        out[s * 128 + 4*jg + 2] = yc2;
        out[s * 128 + 4*jg + 3] = yc3;
    }
    if (t == 0) {
        float TRs = 0.f, DOs = 0.f;
#pragma unroll
        for (int ww = 0; ww < 8; ++ww) { TRs += redA[ww]; DOs += redB[ww]; }
        const float TR = TRs * dt;                  // each col counted once
        const float DO = DOs * dt * (1.f / 16.f);   // 16x lane replication
        const float LOG2PI = 1.8378770664093454f;
        float lpx0 = -0.5f * (sqred[0] + sqred[1]) - 0.5f * 128.f * LOG2PI;
        out[nB * 128 + s]      = lpx0 - TR;
        out[nB * 128 + nB + s] = DO - TR;
    }
}

extern "C" void kernel_launch(void* const* d_in, const int* in_sizes, int n_in,
                              void* d_out, int out_size, void* d_ws, size_t ws_size,
                              hipStream_t stream) {
    const float* x0 = (const float*)d_in[0];
    const float* W1 = (const float*)d_in[1];
    const float* b1 = (const float*)d_in[2];
    const float* u1 = (const float*)d_in[3];
    const float* W2 = (const float*)d_in[4];
    const float* b2 = (const float*)d_in[5];
    const int*  nsp = (const int*)d_in[6];
    float* out = (float*)d_out;
    const int nB = in_sizes[0] / 128;   // 128 samples

    hipLaunchKernelGGL(vi_node_kernel, dim3(nB), dim3(TPB), 0, stream,
                       x0, W1, b1, u1, W2, b2, nsp, out, nB);
}